// Round 1
// baseline (364.021 us; speedup 1.0000x reference)
//
#include <hip/hip_runtime.h>
#include <hip/hip_bf16.h>
#include <stdint.h>

// Problem constants
#define B_ROWS 32768
#define NUM_IN 1024
#define D_PAD  1088   // 1064 padded to multiple of 64
#define HID    2048
#define NPAD   64     // 37 logits padded to 64

typedef __attribute__((ext_vector_type(8))) short bf16x8;
typedef __attribute__((ext_vector_type(4))) float f32x4;

__device__ __forceinline__ unsigned short f2bf(float f){
  union { float f; uint32_t u; } x; x.f = f;
  uint32_t u = x.u;
  return (unsigned short)((u + 0x7FFFu + ((u >> 16) & 1u)) >> 16);
}

__device__ __forceinline__ void gload16(const void* g, void* l){
  __builtin_amdgcn_global_load_lds((const __attribute__((address_space(1))) void*)g,
                                   (__attribute__((address_space(3))) void*)l, 16, 0, 0);
}

// ---------------- discretizer scan (per batch element) ----------------
__device__ __forceinline__ int disc_step(
    float cam0, float cam1, const int a[5],
    float& ac0, float& ac1, float& delta,
    int r[5], bool& dch, int& cam_steps, bool& committed, float& norm)
{
  const int RS[5] = {6, 8, 10, 11, 14};
  norm += committed ? 0.0f : 1.0f;
  bool commit = ((fabsf(cam0) < 1e-5f) && (fabsf(cam1) < 1e-5f)) || (cam_steps >= 6);
  #pragma unroll
  for (int i = 0; i < 5; ++i) commit = commit && (r[i] == a[i]);
  int dac = 0;
  bool modified = commit;
  #pragma unroll
  for (int i = 0; i < 5; ++i){
    bool disc = (!modified) && (r[i] != a[i]);
    if (disc){
      dac = (a[i] == 0) ? (r[i] - 1 + RS[i]) : (a[i] - 1 + RS[i]);
      r[i] = a[i];
      modified = true;
    }
  }
  float d2 = delta * 2.0f;
  // NOTE: reference compares BOTH cam0 and cam1 against ac[:,0] — replicate.
  bool dmask = (!modified) && (!dch) &&
               ((fabsf(cam0 - ac0) > d2) || (fabsf(cam1 - ac0) > d2));
  if (dmask){ dac = 5; delta = fminf(d2, 0.5f); modified = true; }
  if (!modified){
    float sx = (cam0 < ac0) ? -1.0f : 1.0f;
    float sy = (cam1 < ac1) ? -1.0f : 1.0f;
    dac = (sx < 0.0f) ? ((sy < 0.0f) ? 1 : 3) : ((sy < 0.0f) ? 2 : 4);
    ac0 += sx * delta; ac1 += sy * delta;
    delta *= 0.5f;
    dch = true;
    cam_steps += 1;
  }
  committed = committed || commit;
  return dac;
}

__global__ void k_disc(const float* __restrict__ camera, const float* __restrict__ rand_u,
                       const int* __restrict__ afb, const int* __restrict__ alr,
                       const int* __restrict__ ajp, const int* __restrict__ ass,
                       const int* __restrict__ aat,
                       unsigned short* __restrict__ xb, int* __restrict__ tgt)
{
  int row = blockIdx.x * 256 + threadIdx.x;
  if (row >= B_ROWS) return;
  float cam0 = camera[2*row], cam1 = camera[2*row + 1];
  int a[5] = { afb[row], alr[row], ajp[row], ass[row], aat[row] };

  // pass 1: compute norm
  float ac0 = 0.f, ac1 = 0.f, delta = 0.0625f, norm = 0.f;
  int r[5] = {0,0,0,0,0};
  bool dch = false, committed = false; int cam_steps = 0;
  for (int t = 0; t < 20; ++t)
    disc_step(cam0, cam1, a, ac0, ac1, delta, r, dch, cam_steps, committed, norm);

  int rs = (int)(rand_u[row] * norm);
  if (rs > 19) rs = 19;
  if (rs < 0) rs = 0;

  // pass 2: advance rs steps, emit entry state, then step rs for dac
  ac0 = 0.f; ac1 = 0.f; delta = 0.0625f; norm = 0.f;
  r[0]=r[1]=r[2]=r[3]=r[4]=0; dch = false; committed = false; cam_steps = 0;
  for (int t = 0; t < rs; ++t)
    disc_step(cam0, cam1, a, ac0, ac1, delta, r, dch, cam_steps, committed, norm);

  float vec[40];
  #pragma unroll
  for (int j = 0; j < 40; ++j) vec[j] = 0.0f;
  vec[0] = ac0; vec[1] = ac1;
  const int offs[5] = {2, 5, 8, 10, 14};
  #pragma unroll
  for (int i = 0; i < 5; ++i) vec[offs[i] + r[i]] = 1.0f;
  vec[38] = delta; vec[39] = dch ? 1.0f : 0.0f;

  int dac = disc_step(cam0, cam1, a, ac0, ac1, delta, r, dch, cam_steps, committed, norm);
  tgt[row] = dac;

  unsigned short* o = xb + (size_t)row * D_PAD + NUM_IN;
  #pragma unroll
  for (int j = 0; j < 40; ++j) o[j] = f2bf(vec[j]);
  #pragma unroll
  for (int j = 40; j < 64; ++j) o[j] = 0;
}

// ---------------- conversions ----------------
__global__ void k_fc(const float* __restrict__ fc, unsigned short* __restrict__ xb)
{
  int gid = blockIdx.x * 256 + threadIdx.x;     // B*1024/8 = 4194304 total
  int row = gid >> 7;                           // 128 8-elt chunks per row
  int c   = gid & 127;
  const float4* p = (const float4*)(fc + (size_t)row * NUM_IN + c * 8);
  float4 f0 = p[0], f1 = p[1];
  unsigned short o[8] = { f2bf(f0.x), f2bf(f0.y), f2bf(f0.z), f2bf(f0.w),
                          f2bf(f1.x), f2bf(f1.y), f2bf(f1.z), f2bf(f1.w) };
  uint4 pk;
  pk.x = (uint32_t)o[0] | ((uint32_t)o[1] << 16);
  pk.y = (uint32_t)o[2] | ((uint32_t)o[3] << 16);
  pk.z = (uint32_t)o[4] | ((uint32_t)o[5] << 16);
  pk.w = (uint32_t)o[6] | ((uint32_t)o[7] << 16);
  *(uint4*)(xb + (size_t)row * D_PAD + c * 8) = pk;
}

__global__ void k_w1t(const float* __restrict__ W1, unsigned short* __restrict__ w1t)
{
  int idx = blockIdx.x * 256 + threadIdx.x;     // over 2048*1088
  if (idx >= HID * D_PAD) return;
  int n = idx / D_PAD;
  int k = idx - n * D_PAD;
  float v = (k < 1064) ? W1[(size_t)k * HID + n] : 0.0f;
  w1t[idx] = f2bf(v);
}

__global__ void k_w2t(const float* __restrict__ W2, unsigned short* __restrict__ w2t)
{
  int idx = blockIdx.x * 256 + threadIdx.x;     // over 64*2048
  if (idx >= NPAD * HID) return;
  int n = idx >> 11;
  int k = idx & (HID - 1);
  float v = (n < 37) ? W2[(size_t)k * 37 + n] : 0.0f;
  w2t[idx] = f2bf(v);
}

// ---------------- GEMM1: h = silu(x @ W1 + b1), bf16 out ----------------
__global__ __launch_bounds__(256) void k_gemm1(const unsigned short* __restrict__ xb,
                                               const unsigned short* __restrict__ w1t,
                                               const float* __restrict__ b1,
                                               unsigned short* __restrict__ hb)
{
  __shared__ __align__(16) unsigned short As[128 * 64];  // [m][k]
  __shared__ __align__(16) unsigned short Bs[128 * 64];  // [n][k]
  const int t = threadIdx.x;
  const int lane = t & 63, wid = t >> 6;
  const int wm = wid >> 1, wn = wid & 1;
  const int lr = lane & 15, lg = lane >> 4;
  const int row0 = blockIdx.x * 128;
  const int col0 = blockIdx.y * 128;
  f32x4 acc[4][4] = {};

  for (int kt = 0; kt < D_PAD / 64; ++kt){
    const int k0 = kt * 64;
    #pragma unroll
    for (int i = 0; i < 4; ++i){
      int c = i * 256 + t, r = c >> 3, cc = c & 7;
      gload16(xb  + (size_t)(row0 + r) * D_PAD + k0 + cc * 8, As + c * 8);
      gload16(w1t + (size_t)(col0 + r) * D_PAD + k0 + cc * 8, Bs + c * 8);
    }
    __syncthreads();
    #pragma unroll
    for (int kk = 0; kk < 2; ++kk){
      bf16x8 a[4], b[4];
      #pragma unroll
      for (int mi = 0; mi < 4; ++mi)
        a[mi] = *(const bf16x8*)(As + (wm*64 + mi*16 + lr) * 64 + kk*32 + lg*8);
      #pragma unroll
      for (int ni = 0; ni < 4; ++ni)
        b[ni] = *(const bf16x8*)(Bs + (wn*64 + ni*16 + lr) * 64 + kk*32 + lg*8);
      #pragma unroll
      for (int mi = 0; mi < 4; ++mi)
        #pragma unroll
        for (int ni = 0; ni < 4; ++ni)
          acc[mi][ni] = __builtin_amdgcn_mfma_f32_16x16x32_bf16(a[mi], b[ni], acc[mi][ni], 0, 0, 0);
    }
    __syncthreads();
  }

  #pragma unroll
  for (int ni = 0; ni < 4; ++ni){
    const int col = col0 + wn*64 + ni*16 + lr;
    const float bias = b1[col];
    #pragma unroll
    for (int mi = 0; mi < 4; ++mi){
      #pragma unroll
      for (int i2 = 0; i2 < 4; ++i2){
        const int row = row0 + wm*64 + mi*16 + lg*4 + i2;
        float v = acc[mi][ni][i2] + bias;
        float s = v / (1.0f + __expf(-v));     // silu
        hb[(size_t)row * HID + col] = f2bf(s);
      }
    }
  }
}

// ---------------- GEMM2 + log-softmax + NLL ----------------
__global__ __launch_bounds__(256) void k_gemm2(const unsigned short* __restrict__ hb,
                                               const unsigned short* __restrict__ w2t,
                                               const float* __restrict__ b2,
                                               const int* __restrict__ tgt,
                                               float* __restrict__ loss)
{
  __shared__ __align__(16) unsigned short As[128 * 64];  // [m][k]
  __shared__ __align__(16) unsigned short Bs[64 * 64];   // [n][k]
  const int t = threadIdx.x;
  const int lane = t & 63, wid = t >> 6;
  const int lr = lane & 15, lg = lane >> 4;
  const int row0 = blockIdx.x * 128;
  f32x4 acc[2][4] = {};

  for (int kt = 0; kt < HID / 64; ++kt){
    const int k0 = kt * 64;
    #pragma unroll
    for (int i = 0; i < 4; ++i){
      int c = i * 256 + t, r = c >> 3, cc = c & 7;
      gload16(hb + (size_t)(row0 + r) * HID + k0 + cc * 8, As + c * 8);
    }
    #pragma unroll
    for (int i = 0; i < 2; ++i){
      int c = i * 256 + t, r = c >> 3, cc = c & 7;
      gload16(w2t + (size_t)r * HID + k0 + cc * 8, Bs + c * 8);
    }
    __syncthreads();
    #pragma unroll
    for (int kk = 0; kk < 2; ++kk){
      bf16x8 a[2], b[4];
      #pragma unroll
      for (int mi = 0; mi < 2; ++mi)
        a[mi] = *(const bf16x8*)(As + (wid*32 + mi*16 + lr) * 64 + kk*32 + lg*8);
      #pragma unroll
      for (int ni = 0; ni < 4; ++ni)
        b[ni] = *(const bf16x8*)(Bs + (ni*16 + lr) * 64 + kk*32 + lg*8);
      #pragma unroll
      for (int mi = 0; mi < 2; ++mi)
        #pragma unroll
        for (int ni = 0; ni < 4; ++ni)
          acc[mi][ni] = __builtin_amdgcn_mfma_f32_16x16x32_bf16(a[mi], b[ni], acc[mi][ni], 0, 0, 0);
    }
    __syncthreads();
  }

  float bias_n[4];
  #pragma unroll
  for (int ni = 0; ni < 4; ++ni){
    int col = ni*16 + lr;
    bias_n[ni] = (col < 37) ? b2[col] : 0.0f;
  }

  #pragma unroll
  for (int mi = 0; mi < 2; ++mi){
    #pragma unroll
    for (int i2 = 0; i2 < 4; ++i2){
      const int row = row0 + wid*32 + mi*16 + lg*4 + i2;
      float v[4]; float m = -1e30f;
      #pragma unroll
      for (int ni = 0; ni < 4; ++ni){
        int col = ni*16 + lr;
        float x = (col < 37) ? (acc[mi][ni][i2] + bias_n[ni]) : -1e30f;
        v[ni] = x; m = fmaxf(m, x);
      }
      #pragma unroll
      for (int off = 1; off < 16; off <<= 1) m = fmaxf(m, __shfl_xor(m, off, 64));
      float se = 0.0f;
      #pragma unroll
      for (int ni = 0; ni < 4; ++ni) se += __expf(v[ni] - m);  // padded cols underflow to 0
      #pragma unroll
      for (int off = 1; off < 16; off <<= 1) se += __shfl_xor(se, off, 64);
      const int tg = tgt[row];
      float pick = 0.0f;
      #pragma unroll
      for (int ni = 0; ni < 4; ++ni){
        int col = ni*16 + lr;
        pick += (col == tg) ? v[ni] : 0.0f;
      }
      #pragma unroll
      for (int off = 1; off < 16; off <<= 1) pick += __shfl_xor(pick, off, 64);
      if (lr == 0) loss[row] = m + __logf(se) - pick;
    }
  }
}

// ---------------- launch ----------------
extern "C" void kernel_launch(void* const* d_in, const int* in_sizes, int n_in,
                              void* d_out, int out_size, void* d_ws, size_t ws_size,
                              hipStream_t stream)
{
  (void)in_sizes; (void)n_in; (void)out_size; (void)ws_size;
  const float* fc  = (const float*)d_in[0];
  const float* cam = (const float*)d_in[1];
  const float* ru  = (const float*)d_in[2];
  const float* W1  = (const float*)d_in[3];
  const float* b1  = (const float*)d_in[4];
  const float* W2  = (const float*)d_in[5];
  const float* b2  = (const float*)d_in[6];
  const int* afb = (const int*)d_in[7];
  const int* alr = (const int*)d_in[8];
  const int* ajp = (const int*)d_in[9];
  const int* ass = (const int*)d_in[10];
  const int* aat = (const int*)d_in[11];
  float* loss = (float*)d_out;

  // workspace layout (bytes, all 256-aligned):
  // xb  : B x 1088 bf16           = 71,303,168
  // w1t : 2048 x 1088 bf16        =  4,456,448
  // w2t : 64 x 2048 bf16          =    262,144
  // tgt : B int32                 =    131,072
  // hb  : B x 2048 bf16           = 134,217,728   (total ~200.6 MiB)
  char* ws = (char*)d_ws;
  unsigned short* xb  = (unsigned short*)(ws);
  unsigned short* w1t = (unsigned short*)(ws + 71303168);
  unsigned short* w2t = (unsigned short*)(ws + 75759616);
  int*            tgt = (int*)           (ws + 76021760);
  unsigned short* hb  = (unsigned short*)(ws + 76152832);

  k_fc  <<<16384, 256, 0, stream>>>(fc, xb);
  k_w1t <<<(HID * D_PAD + 255) / 256, 256, 0, stream>>>(W1, w1t);
  k_w2t <<<(NPAD * HID + 255) / 256, 256, 0, stream>>>(W2, w2t);
  k_disc<<<(B_ROWS + 255) / 256, 256, 0, stream>>>(cam, ru, afb, alr, ajp, ass, aat, xb, tgt);

  dim3 g1(B_ROWS / 128, HID / 128);
  k_gemm1<<<g1, 256, 0, stream>>>(xb, w1t, b1, hb);
  k_gemm2<<<B_ROWS / 128, 256, 0, stream>>>(hb, w2t, b2, tgt, loss);
}

// Round 2
// 275.044 us; speedup vs baseline: 1.3235x; 1.3235x over previous
//
#include <hip/hip_runtime.h>
#include <hip/hip_bf16.h>
#include <stdint.h>

// Problem constants
#define B_ROWS 32768
#define NUM_IN 1024
#define D_PAD2 1152   // 1064 padded to 18*64 (even # of 64-wide K tiles)
#define HID    2048
#define NPAD   64     // 37 logits padded to 64

typedef __attribute__((ext_vector_type(8))) short bf16x8;
typedef __attribute__((ext_vector_type(4))) float f32x4;
typedef unsigned short ushort_t;

__device__ __forceinline__ unsigned short f2bf(float f){
  union { float f; uint32_t u; } x; x.f = f;
  uint32_t u = x.u;
  return (unsigned short)((u + 0x7FFFu + ((u >> 16) & 1u)) >> 16);
}

__device__ __forceinline__ void gload16(const void* g, void* l){
  __builtin_amdgcn_global_load_lds((const __attribute__((address_space(1))) void*)g,
                                   (__attribute__((address_space(3))) void*)l, 16, 0, 0);
}

// ---------------- discretizer scan (per batch element) ----------------
__device__ __forceinline__ int disc_step(
    float cam0, float cam1, const int a[5],
    float& ac0, float& ac1, float& delta,
    int r[5], bool& dch, int& cam_steps, bool& committed, float& norm)
{
  const int RS[5] = {6, 8, 10, 11, 14};
  norm += committed ? 0.0f : 1.0f;
  bool commit = ((fabsf(cam0) < 1e-5f) && (fabsf(cam1) < 1e-5f)) || (cam_steps >= 6);
  #pragma unroll
  for (int i = 0; i < 5; ++i) commit = commit && (r[i] == a[i]);
  int dac = 0;
  bool modified = commit;
  #pragma unroll
  for (int i = 0; i < 5; ++i){
    bool disc = (!modified) && (r[i] != a[i]);
    if (disc){
      dac = (a[i] == 0) ? (r[i] - 1 + RS[i]) : (a[i] - 1 + RS[i]);
      r[i] = a[i];
      modified = true;
    }
  }
  float d2 = delta * 2.0f;
  // NOTE: reference compares BOTH cam0 and cam1 against ac[:,0] — replicate.
  bool dmask = (!modified) && (!dch) &&
               ((fabsf(cam0 - ac0) > d2) || (fabsf(cam1 - ac0) > d2));
  if (dmask){ dac = 5; delta = fminf(d2, 0.5f); modified = true; }
  if (!modified){
    float sx = (cam0 < ac0) ? -1.0f : 1.0f;
    float sy = (cam1 < ac1) ? -1.0f : 1.0f;
    dac = (sx < 0.0f) ? ((sy < 0.0f) ? 1 : 3) : ((sy < 0.0f) ? 2 : 4);
    ac0 += sx * delta; ac1 += sy * delta;
    delta *= 0.5f;
    dch = true;
    cam_steps += 1;
  }
  committed = committed || commit;
  return dac;
}

__global__ void k_disc(const float* __restrict__ camera, const float* __restrict__ rand_u,
                       const int* __restrict__ afb, const int* __restrict__ alr,
                       const int* __restrict__ ajp, const int* __restrict__ ass,
                       const int* __restrict__ aat,
                       unsigned short* __restrict__ xb, int* __restrict__ tgt)
{
  int row = blockIdx.x * 256 + threadIdx.x;
  if (row >= B_ROWS) return;
  float cam0 = camera[2*row], cam1 = camera[2*row + 1];
  int a[5] = { afb[row], alr[row], ajp[row], ass[row], aat[row] };

  // pass 1: compute norm
  float ac0 = 0.f, ac1 = 0.f, delta = 0.0625f, norm = 0.f;
  int r[5] = {0,0,0,0,0};
  bool dch = false, committed = false; int cam_steps = 0;
  for (int t = 0; t < 20; ++t)
    disc_step(cam0, cam1, a, ac0, ac1, delta, r, dch, cam_steps, committed, norm);

  int rs = (int)(rand_u[row] * norm);
  if (rs > 19) rs = 19;
  if (rs < 0) rs = 0;

  // pass 2: advance rs steps, emit entry state, then step rs for dac
  ac0 = 0.f; ac1 = 0.f; delta = 0.0625f; norm = 0.f;
  r[0]=r[1]=r[2]=r[3]=r[4]=0; dch = false; committed = false; cam_steps = 0;
  for (int t = 0; t < rs; ++t)
    disc_step(cam0, cam1, a, ac0, ac1, delta, r, dch, cam_steps, committed, norm);

  float vec[40];
  #pragma unroll
  for (int j = 0; j < 40; ++j) vec[j] = 0.0f;
  vec[0] = ac0; vec[1] = ac1;
  const int offs[5] = {2, 5, 8, 10, 14};
  #pragma unroll
  for (int i = 0; i < 5; ++i) vec[offs[i] + r[i]] = 1.0f;
  vec[38] = delta; vec[39] = dch ? 1.0f : 0.0f;

  int dac = disc_step(cam0, cam1, a, ac0, ac1, delta, r, dch, cam_steps, committed, norm);
  tgt[row] = dac;

  unsigned short* o = xb + (size_t)row * D_PAD2 + NUM_IN;
  #pragma unroll
  for (int j = 0; j < 40; ++j) o[j] = f2bf(vec[j]);
  // zero-pad cols 1064..1151
  for (int j = 40; j < D_PAD2 - NUM_IN; ++j) o[j] = 0;
}

// ---------------- conversions ----------------
__global__ void k_fc(const float* __restrict__ fc, unsigned short* __restrict__ xb)
{
  int gid = blockIdx.x * 256 + threadIdx.x;     // B*1024/8 = 4194304 total
  int row = gid >> 7;                           // 128 8-elt chunks per row
  int c   = gid & 127;
  const float4* p = (const float4*)(fc + (size_t)row * NUM_IN + c * 8);
  float4 f0 = p[0], f1 = p[1];
  unsigned short o[8] = { f2bf(f0.x), f2bf(f0.y), f2bf(f0.z), f2bf(f0.w),
                          f2bf(f1.x), f2bf(f1.y), f2bf(f1.z), f2bf(f1.w) };
  uint4 pk;
  pk.x = (uint32_t)o[0] | ((uint32_t)o[1] << 16);
  pk.y = (uint32_t)o[2] | ((uint32_t)o[3] << 16);
  pk.z = (uint32_t)o[4] | ((uint32_t)o[5] << 16);
  pk.w = (uint32_t)o[6] | ((uint32_t)o[7] << 16);
  *(uint4*)(xb + (size_t)row * D_PAD2 + c * 8) = pk;
}

__global__ void k_w1t(const float* __restrict__ W1, unsigned short* __restrict__ w1t)
{
  int idx = blockIdx.x * 256 + threadIdx.x;     // over 2048*1152
  if (idx >= HID * D_PAD2) return;
  int n = idx / D_PAD2;
  int k = idx - n * D_PAD2;
  float v = (k < 1064) ? W1[(size_t)k * HID + n] : 0.0f;
  w1t[idx] = f2bf(v);
}

__global__ void k_w2t(const float* __restrict__ W2, unsigned short* __restrict__ w2t)
{
  int idx = blockIdx.x * 256 + threadIdx.x;     // over 64*2048
  if (idx >= NPAD * HID) return;
  int n = idx >> 11;
  int k = idx & (HID - 1);
  float v = (n < 37) ? W2[(size_t)k * 37 + n] : 0.0f;
  w2t[idx] = f2bf(v);
}

// ---------------- GEMM1: 256x256 8-phase, h = silu(x @ W1 + b1) ----------------
// LDS regions (ushort offsets): even K-tiles in A0/B0, odd in A1/B1.
#define LDS_A0 0
#define LDS_A1 16384
#define LDS_B0 32768
#define LDS_B1 49152

// stage one 128x64 half-tile: 2 x global_load_lds(16B) per thread, 512 threads.
// LDS dest is LINEAR (wave-uniform base + lane*16); the XOR swizzle is realized
// by pre-swizzling the GLOBAL source column chunk (involution, rule #21).
#define STAGE(G, REG, ROW0, KT, HALF) do { \
    const ushort_t* s0_ = (G) + (size_t)((ROW0) + (HALF)*128 + srow) * D_PAD2 + ((KT) << 6) + scol; \
    gload16(s0_, lds + (REG) + (HALF)*8192 + t*8); \
    gload16(s0_ + (size_t)64 * D_PAD2, lds + (REG) + (HALF)*8192 + 4096 + t*8); \
  } while(0)

// fragment reads: byte chunk index = (kk*4+lg) ^ (row&7); row&7 == lr&7 here.
#define LDA_(REG, MH) do { \
    _Pragma("unroll") for (int mi_ = 0; mi_ < 4; ++mi_){ \
      const int row_ = arow_base + (MH)*64 + mi_*16; \
      _Pragma("unroll") for (int kk_ = 0; kk_ < 2; ++kk_) \
        aR[mi_][kk_] = *(const bf16x8*)(lds + (REG) + row_*64 + (((kk_*4+lg)^axor)<<3)); \
    } \
  } while(0)

#define LDB_(REG, NH, BR) do { \
    _Pragma("unroll") for (int ni_ = 0; ni_ < 2; ++ni_){ \
      const int row_ = brow_base + (NH)*32 + ni_*16; \
      _Pragma("unroll") for (int kk_ = 0; kk_ < 2; ++kk_) \
        BR[ni_][kk_] = *(const bf16x8*)(lds + (REG) + row_*64 + (((kk_*4+lg)^axor)<<3)); \
    } \
  } while(0)

#define MMA(MH, NH, BR) do { \
    __builtin_amdgcn_s_setprio(1); \
    _Pragma("unroll") for (int mi_ = 0; mi_ < 4; ++mi_) \
    _Pragma("unroll") for (int ni_ = 0; ni_ < 2; ++ni_) \
    _Pragma("unroll") for (int kk_ = 0; kk_ < 2; ++kk_) \
      acc[(MH)*4+mi_][(NH)*2+ni_] = __builtin_amdgcn_mfma_f32_16x16x32_bf16( \
          aR[mi_][kk_], BR[ni_][kk_], acc[(MH)*4+mi_][(NH)*2+ni_], 0, 0, 0); \
    __builtin_amdgcn_s_setprio(0); \
  } while(0)

#define BAR() __builtin_amdgcn_s_barrier()
#define WAIT_LGKM0() asm volatile("s_waitcnt lgkmcnt(0)" ::: "memory")
#define WAIT_VM6()   asm volatile("s_waitcnt vmcnt(6)" ::: "memory")

__global__ __launch_bounds__(512, 2) void k_gemm1(const ushort_t* __restrict__ xb,
                                                  const ushort_t* __restrict__ w1t,
                                                  const float* __restrict__ b1,
                                                  ushort_t* __restrict__ hb)
{
  __shared__ ushort_t lds[65536];   // 128 KiB
  const int t = threadIdx.x;        // 0..511
  const int lane = t & 63;
  const int wid = t >> 6, wm = wid >> 2, wn = wid & 3;
  const int lr = lane & 15, lg = lane >> 4;

  // XCD-aware swizzle (nwg=1024 divisible by 8 -> bijective).
  // col-tile fastest within an XCD chunk: 8 consecutive blocks share one A panel.
  const int bid = blockIdx.x;
  const int swz = (bid & 7) * 128 + (bid >> 3);
  const int brow = (swz >> 3) << 8;   // 128 row tiles of 256
  const int bcol = (swz & 7) << 8;    // 8 col tiles of 256

  // staging coords
  const int srow = t >> 3;                          // 0..63
  const int scol = ((t & 7) ^ (srow & 7)) << 3;     // pre-swizzled source chunk

  // fragment coords
  const int axor = lr & 7;
  const int arow_base = wm*128 + lr;
  const int brow_base = wn*64 + lr;

  f32x4 acc[8][4] = {};
  bf16x8 aR[4][2], bR0[2][2], bR1[2][2];

  // ---- prologue: tile0 -> buf0 (4 halves), tile1 -> buf1 (B h0,h1 + A h0)
  STAGE(xb,  LDS_A0, brow, 0, 0);  STAGE(xb,  LDS_A0, brow, 0, 1);
  STAGE(w1t, LDS_B0, bcol, 0, 0);  STAGE(w1t, LDS_B0, bcol, 0, 1);
  STAGE(w1t, LDS_B1, bcol, 1, 0);  STAGE(w1t, LDS_B1, bcol, 1, 1);
  STAGE(xb,  LDS_A1, brow, 1, 0);
  WAIT_VM6();            // 14 loads issued, <=6 outstanding -> tile0 landed
  BAR();

  for (int i = 0; i < 9; ++i){
    const int c1 = 2*i + 1;
    const int n0 = (2*i + 2 <= 17) ? 2*i + 2 : 16;  // clamp: re-stages same data, benign
    const int n1 = (2*i + 3 <= 17) ? 2*i + 3 : 17;

    // ph1: read A0(mh0) + ALL B0; stage A1.h1 (tile c1)
    LDA_(LDS_A0, 0); LDB_(LDS_B0, 0, bR0); LDB_(LDS_B0, 1, bR1);
    STAGE(xb, LDS_A1, brow, c1, 1);
    BAR(); WAIT_LGKM0();
    MMA(0, 0, bR0);
    BAR();
    // ph2: stage B0.h0 (tile n0; B0 region free after ph1)
    STAGE(w1t, LDS_B0, bcol, n0, 0);
    BAR();
    MMA(0, 1, bR1);
    BAR();
    // ph3: read A0(mh1); stage B0.h1
    LDA_(LDS_A0, 1);
    STAGE(w1t, LDS_B0, bcol, n0, 1);
    BAR(); WAIT_LGKM0();
    MMA(1, 0, bR0);
    BAR();
    // ph4: stage A0.h0 (A0 free after ph3); counted vmcnt -> tile c1 landed
    STAGE(xb, LDS_A0, brow, n0, 0);
    WAIT_VM6();
    BAR();
    MMA(1, 1, bR1);
    BAR();
    // ph5: read A1(mh0) + ALL B1 (tile c1); stage A0.h1
    LDA_(LDS_A1, 0); LDB_(LDS_B1, 0, bR0); LDB_(LDS_B1, 1, bR1);
    STAGE(xb, LDS_A0, brow, n0, 1);
    BAR(); WAIT_LGKM0();
    MMA(0, 0, bR0);
    BAR();
    // ph6: stage B1.h0 (tile n1; B1 free after ph5)
    STAGE(w1t, LDS_B1, bcol, n1, 0);
    BAR();
    MMA(0, 1, bR1);
    BAR();
    // ph7: read A1(mh1); stage B1.h1
    LDA_(LDS_A1, 1);
    STAGE(w1t, LDS_B1, bcol, n1, 1);
    BAR(); WAIT_LGKM0();
    MMA(1, 0, bR0);
    BAR();
    // ph8: stage A1.h0 (A1 free after ph7); counted vmcnt -> tile n0 landed
    STAGE(xb, LDS_A1, brow, n1, 0);
    WAIT_VM6();
    BAR();
    MMA(1, 1, bR1);
    BAR();
  }

  // ---- epilogue: bias + silu, bf16 store
  #pragma unroll
  for (int ni = 0; ni < 4; ++ni){
    const int col = bcol + wn*64 + ni*16 + lr;
    const float bias = b1[col];
    #pragma unroll
    for (int mi = 0; mi < 8; ++mi){
      #pragma unroll
      for (int i2 = 0; i2 < 4; ++i2){
        const int row = brow + wm*128 + mi*16 + lg*4 + i2;
        float v = acc[mi][ni][i2] + bias;
        float s = v / (1.0f + __expf(-v));     // silu
        hb[(size_t)row * HID + col] = f2bf(s);
      }
    }
  }
}

// ---------------- GEMM2 + log-softmax + NLL ----------------
__global__ __launch_bounds__(256) void k_gemm2(const unsigned short* __restrict__ hb,
                                               const unsigned short* __restrict__ w2t,
                                               const float* __restrict__ b2,
                                               const int* __restrict__ tgt,
                                               float* __restrict__ loss)
{
  __shared__ __align__(16) unsigned short As[128 * 64];  // [m][k]
  __shared__ __align__(16) unsigned short Bs[64 * 64];   // [n][k]
  const int t = threadIdx.x;
  const int lane = t & 63, wid = t >> 6;
  const int lr = lane & 15, lg = lane >> 4;
  const int row0 = blockIdx.x * 128;
  f32x4 acc[2][4] = {};

  for (int kt = 0; kt < HID / 64; ++kt){
    const int k0 = kt * 64;
    #pragma unroll
    for (int i = 0; i < 4; ++i){
      int c = i * 256 + t, r = c >> 3, cc = c & 7;
      gload16(hb + (size_t)(row0 + r) * HID + k0 + cc * 8, As + c * 8);
    }
    #pragma unroll
    for (int i = 0; i < 2; ++i){
      int c = i * 256 + t, r = c >> 3, cc = c & 7;
      gload16(w2t + (size_t)r * HID + k0 + cc * 8, Bs + c * 8);
    }
    __syncthreads();
    #pragma unroll
    for (int kk = 0; kk < 2; ++kk){
      bf16x8 a[2], b[4];
      #pragma unroll
      for (int mi = 0; mi < 2; ++mi)
        a[mi] = *(const bf16x8*)(As + (wid*32 + mi*16 + lr) * 64 + kk*32 + lg*8);
      #pragma unroll
      for (int ni = 0; ni < 4; ++ni)
        b[ni] = *(const bf16x8*)(Bs + (ni*16 + lr) * 64 + kk*32 + lg*8);
      #pragma unroll
      for (int mi = 0; mi < 2; ++mi)
        #pragma unroll
        for (int ni = 0; ni < 4; ++ni)
          acc[mi][ni] = __builtin_amdgcn_mfma_f32_16x16x32_bf16(a[mi], b[ni], acc[mi][ni], 0, 0, 0);
    }
    __syncthreads();
  }

  float bias_n[4];
  #pragma unroll
  for (int ni = 0; ni < 4; ++ni){
    int col = ni*16 + lr;
    bias_n[ni] = (col < 37) ? b2[col] : 0.0f;
  }

  #pragma unroll
  for (int mi = 0; mi < 2; ++mi){
    #pragma unroll
    for (int i2 = 0; i2 < 4; ++i2){
      const int row = row0 + wid*32 + mi*16 + lg*4 + i2;
      float v[4]; float m = -1e30f;
      #pragma unroll
      for (int ni = 0; ni < 4; ++ni){
        int col = ni*16 + lr;
        float x = (col < 37) ? (acc[mi][ni][i2] + bias_n[ni]) : -1e30f;
        v[ni] = x; m = fmaxf(m, x);
      }
      #pragma unroll
      for (int off = 1; off < 16; off <<= 1) m = fmaxf(m, __shfl_xor(m, off, 64));
      float se = 0.0f;
      #pragma unroll
      for (int ni = 0; ni < 4; ++ni) se += __expf(v[ni] - m);  // padded cols underflow to 0
      #pragma unroll
      for (int off = 1; off < 16; off <<= 1) se += __shfl_xor(se, off, 64);
      const int tg = tgt[row];
      float pick = 0.0f;
      #pragma unroll
      for (int ni = 0; ni < 4; ++ni){
        int col = ni*16 + lr;
        pick += (col == tg) ? v[ni] : 0.0f;
      }
      #pragma unroll
      for (int off = 1; off < 16; off <<= 1) pick += __shfl_xor(pick, off, 64);
      if (lr == 0) loss[row] = m + __logf(se) - pick;
    }
  }
}

// ---------------- launch ----------------
extern "C" void kernel_launch(void* const* d_in, const int* in_sizes, int n_in,
                              void* d_out, int out_size, void* d_ws, size_t ws_size,
                              hipStream_t stream)
{
  (void)in_sizes; (void)n_in; (void)out_size; (void)ws_size;
  const float* fc  = (const float*)d_in[0];
  const float* cam = (const float*)d_in[1];
  const float* ru  = (const float*)d_in[2];
  const float* W1  = (const float*)d_in[3];
  const float* b1  = (const float*)d_in[4];
  const float* W2  = (const float*)d_in[5];
  const float* b2  = (const float*)d_in[6];
  const int* afb = (const int*)d_in[7];
  const int* alr = (const int*)d_in[8];
  const int* ajp = (const int*)d_in[9];
  const int* ass = (const int*)d_in[10];
  const int* aat = (const int*)d_in[11];
  float* loss = (float*)d_out;

  // workspace layout (bytes):
  // xb  : 32768 x 1152 bf16 = 75,497,472
  // w1t : 2048 x 1152 bf16  =  4,718,592
  // w2t : 64 x 2048 bf16    =    262,144
  // tgt : 32768 int32       =    131,072
  // hb  : 32768 x 2048 bf16 = 134,217,728   (total ~205 MiB)
  char* ws = (char*)d_ws;
  unsigned short* xb  = (unsigned short*)(ws);
  unsigned short* w1t = (unsigned short*)(ws + 75497472);
  unsigned short* w2t = (unsigned short*)(ws + 80216064);
  int*            tgt = (int*)           (ws + 80478208);
  unsigned short* hb  = (unsigned short*)(ws + 80609280);

  k_fc  <<<16384, 256, 0, stream>>>(fc, xb);
  k_w1t <<<(HID * D_PAD2 + 255) / 256, 256, 0, stream>>>(W1, w1t);
  k_w2t <<<(NPAD * HID + 255) / 256, 256, 0, stream>>>(W2, w2t);
  k_disc<<<(B_ROWS + 255) / 256, 256, 0, stream>>>(cam, ru, afb, alr, ajp, ass, aat, xb, tgt);

  k_gemm1<<<(B_ROWS/256) * (HID/256), 512, 0, stream>>>(xb, w1t, b1, hb);
  k_gemm2<<<B_ROWS / 128, 256, 0, stream>>>(hb, w2t, b2, tgt, loss);
}